// Round 15
// baseline (1331.660 us; speedup 1.0000x reference)
//
#include <hip/hip_runtime.h>
#include <hip/hip_cooperative_groups.h>
#include <math.h>

namespace cg = cooperative_groups;

#define N_NODES 50000
#define N_EDGES 800000
#define HID 16
#define SCAN_BLOCKS ((N_NODES + 255) / 256)   // 196
#define COOP_BLOCKS 512                       // 2 blocks/CU * 256 CU (guaranteed co-resident at <=256 VGPR)
#define BLK 256

// ---------------------------------------------------------------------------
// shared phase bodies (used by both the cooperative mega-kernel and the
// discrete fallback kernels)
// ---------------------------------------------------------------------------
__device__ __forceinline__ void count_body(const int* __restrict__ src,
                                           const int* __restrict__ dst,
                                           const int* __restrict__ region,
                                           int* __restrict__ cnt_all,
                                           int* __restrict__ cnt_act,
                                           int tid, int stride) {
    for (int e = tid; e < N_EDGES; e += stride) {
        int s = src[e];
        int d = dst[e];
        atomicAdd(cnt_all + d, 1);
        if (region[s] == region[d]) atomicAdd(cnt_act + d, 1);
    }
}

__device__ __forceinline__ void fill_body(const int* __restrict__ src,
                                          const int* __restrict__ dst,
                                          const int* __restrict__ region,
                                          const int* __restrict__ row_ptr,
                                          int* __restrict__ cursor,
                                          int* __restrict__ csr_eid,
                                          int tid, int stride) {
    for (int e = tid; e < N_EDGES; e += stride) {
        int s = src[e];
        int d = dst[e];
        if (region[s] == region[d]) {
            int pos = row_ptr[d] + atomicAdd(cursor + d, 1);
            csr_eid[pos] = e;
        }
    }
}

// per-block tile reduce of cnt_act -> blockSums (blocks [0,SCAN_BLOCKS))
__device__ __forceinline__ void scanA_body(const int* __restrict__ cnt_act,
                                           int* __restrict__ blockSums,
                                           int* lds, int bid) {
    int i = bid * 256 + threadIdx.x;
    lds[threadIdx.x] = (i < N_NODES) ? cnt_act[i] : 0;
    __syncthreads();
    for (int off = 128; off > 0; off >>= 1) {
        if (threadIdx.x < off) lds[threadIdx.x] += lds[threadIdx.x + off];
        __syncthreads();
    }
    if (threadIdx.x == 0) blockSums[bid] = lds[0];
}

// each block redundantly scans the 196 partials, then scans its own tile
__device__ __forceinline__ void scanBC_body(const int* __restrict__ cnt_act,
                                            const int* __restrict__ blockSums,
                                            int* __restrict__ row_ptr,
                                            int* ldsA, int* ldsB, int bid) {
    int t = threadIdx.x;
    ldsB[t] = (t < SCAN_BLOCKS) ? blockSums[t] : 0;
    __syncthreads();
    for (int off = 1; off < 256; off <<= 1) {
        int u = (t >= off) ? ldsB[t - off] : 0;
        __syncthreads();
        ldsB[t] += u;
        __syncthreads();
    }
    int blockOff = (bid == 0) ? 0 : ldsB[bid - 1];

    int i = bid * 256 + t;
    int v = (i < N_NODES) ? cnt_act[i] : 0;
    ldsA[t] = v;
    __syncthreads();
    for (int off = 1; off < 256; off <<= 1) {
        int u = (t >= off) ? ldsA[t - off] : 0;
        __syncthreads();
        ldsA[t] += u;
        __syncthreads();
    }
    if (i < N_NODES) row_ptr[i] = blockOff + ldsA[t] - v;   // exclusive
}

template <int IN_C>
__device__ __forceinline__ void gather_body(const float* __restrict__ x,
                                            const float* __restrict__ hbase,
                                            const int* __restrict__ src,
                                            const int* __restrict__ csr_eid,
                                            const int* __restrict__ row_ptr,
                                            const int* __restrict__ cnt_act,
                                            const int* __restrict__ cnt_all,
                                            const float* __restrict__ Win,
                                            const float* __restrict__ bin,
                                            const float* __restrict__ Wout,
                                            const float* __restrict__ bout,
                                            float* __restrict__ hout,
                                            int tid, int stride) {
    for (int t = tid; t < N_NODES * HID; t += stride) {
        int n = t >> 4;
        int j = t & 15;

        float w0[IN_C], w1[IN_C], bb[IN_C];
#pragma unroll
        for (int c = 0; c < IN_C; ++c) {
            w0[c] = Win[c * HID + j];
            w1[c] = Win[IN_C * HID + c * HID + j];
            bb[c] = bin[c * HID + j];
        }

        float px = x[n * 16 + 0];
        float py = x[n * 16 + 1];
        int beg  = row_ptr[n];
        int cntA = cnt_act[n];

        float msg = 0.0f;
        for (int k = 0; k < cntA; ++k) {
            int e = csr_eid[beg + k];
            int s = src[e];
            float rx = px - x[s * 16 + 0];
            float ry = py - x[s * 16 + 1];
            const float* hs = hbase + s * 16;
            float m = 0.0f;
#pragma unroll
            for (int c = 0; c < IN_C; ++c) {
                float sp = fmaf(rx, w0[c], fmaf(ry, w1[c], bb[c]));
                sp = fmaxf(sp, 0.0f);
                m = fmaf(hs[c], sp, m);
            }
            msg += m;
        }

        float inv = 1.0f / fmaxf((float)cnt_all[n], 1.0f);
        float a = msg * inv;

        int lane_base = (threadIdx.x & 63) & 0x30;
        float o = bout[j];
#pragma unroll
        for (int c = 0; c < HID; ++c) {
            float ac = __shfl(a, lane_base + c, 64);
            o = fmaf(ac, Wout[c * HID + j], o);
        }
        hout[n * HID + j] = fmaxf(o, 0.0f);
    }
}

__device__ __forceinline__ void decoder_body(const float* __restrict__ h,
                                             const int* __restrict__ src,
                                             const int* __restrict__ dst,
                                             const float* __restrict__ Wd1,
                                             const float* __restrict__ bd1,
                                             const float* __restrict__ Wd2,
                                             const float* __restrict__ bd2,
                                             const float* __restrict__ Wd3,
                                             const float* __restrict__ bd3,
                                             float* __restrict__ out,
                                             int tid, int stride) {
    for (int e = tid; e < N_EDGES; e += stride) {
        int s = src[e];
        int d = dst[e];

        float hv[HID];
        float d1[HID];
#pragma unroll
        for (int j = 0; j < HID; ++j) d1[j] = bd1[j];

        const float4* h4 = (const float4*)(h + (size_t)s * HID);
#pragma unroll
        for (int q = 0; q < 4; ++q) {
            float4 v = h4[q];
            hv[q*4+0] = v.x; hv[q*4+1] = v.y; hv[q*4+2] = v.z; hv[q*4+3] = v.w;
        }
#pragma unroll
        for (int c = 0; c < HID; ++c) {
            float hc = hv[c];
#pragma unroll
            for (int j = 0; j < HID; ++j) d1[j] = fmaf(hc, Wd1[c * HID + j], d1[j]);
        }
        h4 = (const float4*)(h + (size_t)d * HID);
#pragma unroll
        for (int q = 0; q < 4; ++q) {
            float4 v = h4[q];
            hv[q*4+0] = v.x; hv[q*4+1] = v.y; hv[q*4+2] = v.z; hv[q*4+3] = v.w;
        }
#pragma unroll
        for (int c = 0; c < HID; ++c) {
            float hc = hv[c];
#pragma unroll
            for (int j = 0; j < HID; ++j) d1[j] = fmaf(hc, Wd1[(HID + c) * HID + j], d1[j]);
        }
#pragma unroll
        for (int j = 0; j < HID; ++j) d1[j] = fmaxf(d1[j], 0.0f);

        float d2[HID];
#pragma unroll
        for (int j = 0; j < HID; ++j) d2[j] = bd2[j];
#pragma unroll
        for (int c = 0; c < HID; ++c) {
            float dc = d1[c];
#pragma unroll
            for (int j = 0; j < HID; ++j) d2[j] = fmaf(dc, Wd2[c * HID + j], d2[j]);
        }

        float o = bd3[0];
#pragma unroll
        for (int j = 0; j < HID; ++j) o = fmaf(fmaxf(d2[j], 0.0f), Wd3[j], o);

        out[e] = 1.0f / (1.0f + __expf(-o));
    }
}

// ---------------------------------------------------------------------------
// cooperative mega-kernel (2 blocks/CU guaranteed: launch_bounds(256,2))
// ---------------------------------------------------------------------------
struct Params {
    const float* x;
    const int* src; const int* dst; const int* region;
    const float *W_in1, *b_in1, *W_out1, *b_out1;
    const float *W_in2, *b_in2, *W_out2, *b_out2;
    const float *W_in3, *b_in3, *W_out3, *b_out3;
    const float *Wd1, *bd1, *Wd2, *bd2, *Wd3, *bd3;
    float* out;
    float *hA, *hB;
    int *cnt_all, *cnt_act, *row_ptr, *cursor, *blockSums;
    int* csr_eid;
};

__global__ __launch_bounds__(BLK, 2) void mega_kernel(Params p) {
    cg::grid_group grid = cg::this_grid();
    const int tid    = blockIdx.x * BLK + threadIdx.x;
    const int stride = COOP_BLOCKS * BLK;

    __shared__ int ldsA[256];
    __shared__ int ldsB[256];

    for (int i = tid; i < N_NODES; i += stride) {
        p.cnt_all[i] = 0;
        p.cnt_act[i] = 0;
        p.cursor[i]  = 0;
    }
    grid.sync();

    count_body(p.src, p.dst, p.region, p.cnt_all, p.cnt_act, tid, stride);
    grid.sync();

    if (blockIdx.x < SCAN_BLOCKS) scanA_body(p.cnt_act, p.blockSums, ldsA, blockIdx.x);
    grid.sync();

    if (blockIdx.x < SCAN_BLOCKS) scanBC_body(p.cnt_act, p.blockSums, p.row_ptr, ldsA, ldsB, blockIdx.x);
    grid.sync();

    fill_body(p.src, p.dst, p.region, p.row_ptr, p.cursor, p.csr_eid, tid, stride);
    grid.sync();

    gather_body<14>(p.x, p.x + 2, p.src, p.csr_eid, p.row_ptr, p.cnt_act, p.cnt_all,
                    p.W_in1, p.b_in1, p.W_out1, p.b_out1, p.hA, tid, stride);
    grid.sync();
    gather_body<16>(p.x, p.hA, p.src, p.csr_eid, p.row_ptr, p.cnt_act, p.cnt_all,
                    p.W_in2, p.b_in2, p.W_out2, p.b_out2, p.hB, tid, stride);
    grid.sync();
    gather_body<16>(p.x, p.hB, p.src, p.csr_eid, p.row_ptr, p.cnt_act, p.cnt_all,
                    p.W_in3, p.b_in3, p.W_out3, p.b_out3, p.hA, tid, stride);
    grid.sync();

    decoder_body(p.hA, p.src, p.dst, p.Wd1, p.bd1, p.Wd2, p.bd2, p.Wd3, p.bd3,
                 p.out, tid, stride);
}

// ---------------------------------------------------------------------------
// discrete fallback kernels (R11-proven structure, scanB+scanC fused)
// ---------------------------------------------------------------------------
__global__ void count_kernel(const int* src, const int* dst, const int* region,
                             int* cnt_all, int* cnt_act) {
    int tid = blockIdx.x * BLK + threadIdx.x;
    count_body(src, dst, region, cnt_all, cnt_act, tid, N_EDGES);
}

__global__ void scanA_kernel(const int* cnt_act, int* blockSums) {
    __shared__ int lds[256];
    scanA_body(cnt_act, blockSums, lds, blockIdx.x);
}

__global__ void scanBC_kernel(const int* cnt_act, const int* blockSums, int* row_ptr) {
    __shared__ int ldsA[256];
    __shared__ int ldsB[256];
    scanBC_body(cnt_act, blockSums, row_ptr, ldsA, ldsB, blockIdx.x);
}

__global__ void fill_kernel(const int* src, const int* dst, const int* region,
                            const int* row_ptr, int* cursor, int* csr_eid) {
    int tid = blockIdx.x * BLK + threadIdx.x;
    fill_body(src, dst, region, row_ptr, cursor, csr_eid, tid, N_EDGES);
}

template <int IN_C>
__global__ void gather_kernel(const float* x, const float* hbase, const int* src,
                              const int* csr_eid, const int* row_ptr,
                              const int* cnt_act, const int* cnt_all,
                              const float* Win, const float* bin,
                              const float* Wout, const float* bout, float* hout) {
    int tid = blockIdx.x * BLK + threadIdx.x;
    gather_body<IN_C>(x, hbase, src, csr_eid, row_ptr, cnt_act, cnt_all,
                      Win, bin, Wout, bout, hout, tid, N_NODES * HID);
}

__global__ void decoder_kernel(const float* h, const int* src, const int* dst,
                               const float* Wd1, const float* bd1,
                               const float* Wd2, const float* bd2,
                               const float* Wd3, const float* bd3, float* out) {
    int tid = blockIdx.x * BLK + threadIdx.x;
    decoder_body(h, src, dst, Wd1, bd1, Wd2, bd2, Wd3, bd3, out, tid, N_EDGES);
}

// ---------------------------------------------------------------------------
extern "C" void kernel_launch(void* const* d_in, const int* in_sizes, int n_in,
                              void* d_out, int out_size, void* d_ws, size_t ws_size,
                              hipStream_t stream) {
    Params p;
    p.x      = (const float*)d_in[0];
    const int* edge = (const int*)d_in[1];
    p.src    = edge;
    p.dst    = edge + N_EDGES;
    p.region = (const int*)d_in[2];
    p.W_in1  = (const float*)d_in[3];  p.b_in1  = (const float*)d_in[4];
    p.W_out1 = (const float*)d_in[5];  p.b_out1 = (const float*)d_in[6];
    p.W_in2  = (const float*)d_in[7];  p.b_in2  = (const float*)d_in[8];
    p.W_out2 = (const float*)d_in[9];  p.b_out2 = (const float*)d_in[10];
    p.W_in3  = (const float*)d_in[11]; p.b_in3  = (const float*)d_in[12];
    p.W_out3 = (const float*)d_in[13]; p.b_out3 = (const float*)d_in[14];
    p.Wd1    = (const float*)d_in[15]; p.bd1    = (const float*)d_in[16];
    p.Wd2    = (const float*)d_in[17]; p.bd2    = (const float*)d_in[18];
    p.Wd3    = (const float*)d_in[19]; p.bd3    = (const float*)d_in[20];
    p.out    = (float*)d_out;

    float* ws   = (float*)d_ws;
    p.hA        = ws;
    p.hB        = p.hA + N_NODES * HID;
    p.cnt_all   = (int*)(p.hB + N_NODES * HID);
    p.cnt_act   = p.cnt_all + N_NODES;
    p.row_ptr   = p.cnt_act + N_NODES;
    p.cursor    = p.row_ptr + N_NODES;
    p.blockSums = p.cursor + N_NODES;
    p.csr_eid   = (int*)d_out;    // decoder overwrites it last

    void* args[] = { &p };
    hipError_t err = hipLaunchCooperativeKernel((void*)mega_kernel,
                                                dim3(COOP_BLOCKS), dim3(BLK),
                                                args, 0, stream);
    if (err != hipSuccess) {
        // discrete fallback (same math, proven structure)
        const int egrid = N_EDGES / BLK;          // 3125
        const int lgrid = N_NODES * HID / BLK;    // 3125
        hipMemsetAsync(p.cnt_all, 0, (size_t)(4 * N_NODES) * sizeof(int), stream);
        count_kernel<<<egrid, BLK, 0, stream>>>(p.src, p.dst, p.region, p.cnt_all, p.cnt_act);
        scanA_kernel<<<SCAN_BLOCKS, 256, 0, stream>>>(p.cnt_act, p.blockSums);
        scanBC_kernel<<<SCAN_BLOCKS, 256, 0, stream>>>(p.cnt_act, p.blockSums, p.row_ptr);
        fill_kernel<<<egrid, BLK, 0, stream>>>(p.src, p.dst, p.region, p.row_ptr, p.cursor, p.csr_eid);
        gather_kernel<14><<<lgrid, BLK, 0, stream>>>(p.x, p.x + 2, p.src, p.csr_eid, p.row_ptr,
                                                     p.cnt_act, p.cnt_all, p.W_in1, p.b_in1,
                                                     p.W_out1, p.b_out1, p.hA);
        gather_kernel<16><<<lgrid, BLK, 0, stream>>>(p.x, p.hA, p.src, p.csr_eid, p.row_ptr,
                                                     p.cnt_act, p.cnt_all, p.W_in2, p.b_in2,
                                                     p.W_out2, p.b_out2, p.hB);
        gather_kernel<16><<<lgrid, BLK, 0, stream>>>(p.x, p.hB, p.src, p.csr_eid, p.row_ptr,
                                                     p.cnt_act, p.cnt_all, p.W_in3, p.b_in3,
                                                     p.W_out3, p.b_out3, p.hA);
        decoder_kernel<<<egrid, BLK, 0, stream>>>(p.hA, p.src, p.dst, p.Wd1, p.bd1,
                                                  p.Wd2, p.bd2, p.Wd3, p.bd3, p.out);
    }
}

// Round 17
// 233.584 us; speedup vs baseline: 5.7010x; 5.7010x over previous
//
#include <hip/hip_runtime.h>
#include <math.h>

#define N_NODES 50000
#define N_EDGES 800000
#define HID 16
#define SCAN_BLOCKS ((N_NODES + 255) / 256)   // 196
#define BLK 256

// ---------------------------------------------------------------------------
// count: cnt_all[dst]++ for EVERY edge; cnt_act[dst]++ for same-region edges.
// ---------------------------------------------------------------------------
__global__ void count_kernel(const int* __restrict__ src,
                             const int* __restrict__ dst,
                             const int* __restrict__ region,
                             int* __restrict__ cnt_all,
                             int* __restrict__ cnt_act) {
    int e = blockIdx.x * BLK + threadIdx.x;
    int s = src[e];
    int d = dst[e];
    atomicAdd(cnt_all + d, 1);
    if (region[s] == region[d]) atomicAdd(cnt_act + d, 1);
}

// ---------------------------------------------------------------------------
// scanA: per-block tile sums of cnt_act
// ---------------------------------------------------------------------------
__global__ void scanA_kernel(const int* __restrict__ cnt_act,
                             int* __restrict__ blockSums) {
    __shared__ int lds[256];
    int i = blockIdx.x * 256 + threadIdx.x;
    lds[threadIdx.x] = (i < N_NODES) ? cnt_act[i] : 0;
    __syncthreads();
    for (int off = 128; off > 0; off >>= 1) {
        if (threadIdx.x < off) lds[threadIdx.x] += lds[threadIdx.x + off];
        __syncthreads();
    }
    if (threadIdx.x == 0) blockSums[blockIdx.x] = lds[0];
}

// ---------------------------------------------------------------------------
// scanBC: each block scans the 196 partials + its own tile ->
//   row_ptr (exclusive), cursor (= row_ptr copy for fill), invDeg (float)
// ---------------------------------------------------------------------------
__global__ void scanBC_kernel(const int* __restrict__ cnt_act,
                              const int* __restrict__ cnt_all,
                              const int* __restrict__ blockSums,
                              int* __restrict__ row_ptr,
                              int* __restrict__ cursor,
                              float* __restrict__ invDeg) {
    __shared__ int ldsA[256];
    __shared__ int ldsB[256];
    int t = threadIdx.x;
    ldsB[t] = (t < SCAN_BLOCKS) ? blockSums[t] : 0;
    __syncthreads();
    for (int off = 1; off < 256; off <<= 1) {
        int u = (t >= off) ? ldsB[t - off] : 0;
        __syncthreads();
        ldsB[t] += u;
        __syncthreads();
    }
    int blockOff = (blockIdx.x == 0) ? 0 : ldsB[blockIdx.x - 1];

    int i = blockIdx.x * 256 + t;
    int v = (i < N_NODES) ? cnt_act[i] : 0;
    ldsA[t] = v;
    __syncthreads();
    for (int off = 1; off < 256; off <<= 1) {
        int u = (t >= off) ? ldsA[t - off] : 0;
        __syncthreads();
        ldsA[t] += u;
        __syncthreads();
    }
    if (i < N_NODES) {
        int rp = blockOff + ldsA[t] - v;     // exclusive
        row_ptr[i] = rp;
        cursor[i]  = rp;                     // fill atomics start here
        invDeg[i]  = 1.0f / fmaxf((float)cnt_all[i], 1.0f);
    }
}

// ---------------------------------------------------------------------------
// fill: per active edge write record {src, rx, ry} into its CSR slot.
// Collapses the gathers' 4-deep load chain (eid->src->x->h) to 2 (rec->h).
// ---------------------------------------------------------------------------
__global__ void fill_kernel(const int* __restrict__ src,
                            const int* __restrict__ dst,
                            const int* __restrict__ region,
                            const float* __restrict__ x,
                            int* __restrict__ cursor,
                            float4* __restrict__ recs) {
    int e = blockIdx.x * BLK + threadIdx.x;
    int s = src[e];
    int d = dst[e];
    if (region[s] == region[d]) {
        int pos = atomicAdd(cursor + d, 1);
        const float2* pd = (const float2*)(x + (size_t)d * 16);
        const float2* ps = (const float2*)(x + (size_t)s * 16);
        float2 xd = *pd;
        float2 xs = *ps;
        float4 rec;
        rec.x = __int_as_float(s);
        rec.y = xd.x - xs.x;                 // rel = pos[dst]-pos[src]
        rec.z = xd.y - xs.y;
        rec.w = 0.0f;
        recs[pos] = rec;
    }
}

// ---------------------------------------------------------------------------
// gather layer: 16 lanes per node, lane j owns channel j. Reads recs (no
// pointer-chase), h via dependent load only. Wout reduce via __shfl.
// grid: 50000*16/256 = 3125 blocks exact.
// ---------------------------------------------------------------------------
template <int IN_C>
__global__ void gather_kernel(const float* __restrict__ hbase,   // stride 16
                              const float4* __restrict__ recs,
                              const int* __restrict__ row_ptr,
                              const int* __restrict__ cnt_act,
                              const float* __restrict__ invDeg,
                              const float* __restrict__ Win,     // (2, IN_C*16)
                              const float* __restrict__ bin,     // (IN_C*16)
                              const float* __restrict__ Wout,    // (16,16)
                              const float* __restrict__ bout,    // (16)
                              float* __restrict__ hout) {
    int t = blockIdx.x * BLK + threadIdx.x;
    int n = t >> 4;
    int j = t & 15;

    float w0[IN_C], w1[IN_C], bb[IN_C];
#pragma unroll
    for (int c = 0; c < IN_C; ++c) {
        w0[c] = Win[c * HID + j];
        w1[c] = Win[IN_C * HID + c * HID + j];
        bb[c] = bin[c * HID + j];
    }

    int beg  = row_ptr[n];
    int cntA = cnt_act[n];

    float msg = 0.0f;
    for (int k = 0; k < cntA; ++k) {
        float4 rec = recs[beg + k];
        int   s  = __float_as_int(rec.x);
        float rx = rec.y;
        float ry = rec.z;
        const float* hs = hbase + (size_t)s * 16;
        float m = 0.0f;
#pragma unroll
        for (int c = 0; c < IN_C; ++c) {
            float sp = fmaf(rx, w0[c], fmaf(ry, w1[c], bb[c]));
            sp = fmaxf(sp, 0.0f);
            m = fmaf(hs[c], sp, m);
        }
        msg += m;
    }

    float a = msg * invDeg[n];

    int lane_base = (threadIdx.x & 63) & 0x30;
    float o = bout[j];
#pragma unroll
    for (int c = 0; c < HID; ++c) {
        float ac = __shfl(a, lane_base + c, 64);
        o = fmaf(ac, Wout[c * HID + j], o);
    }
    hout[n * HID + j] = fmaxf(o, 0.0f);
}

// ---------------------------------------------------------------------------
// decoder: z=[h[src],h[dst]] -> relu(z@Wd1+b1) -> relu(@Wd2+b2) -> sigmoid(@Wd3+b3)
// ---------------------------------------------------------------------------
__global__ void decoder_kernel(const float* __restrict__ h,
                               const int* __restrict__ src,
                               const int* __restrict__ dst,
                               const float* __restrict__ Wd1,  // (32,16)
                               const float* __restrict__ bd1,
                               const float* __restrict__ Wd2,  // (16,16)
                               const float* __restrict__ bd2,
                               const float* __restrict__ Wd3,  // (16,1)
                               const float* __restrict__ bd3,
                               float* __restrict__ out) {
    int e = blockIdx.x * BLK + threadIdx.x;
    int s = src[e];
    int d = dst[e];

    float hv[HID];
    float d1[HID];
#pragma unroll
    for (int j = 0; j < HID; ++j) d1[j] = bd1[j];

    const float4* h4 = (const float4*)(h + (size_t)s * HID);
#pragma unroll
    for (int q = 0; q < 4; ++q) {
        float4 v = h4[q];
        hv[q*4+0] = v.x; hv[q*4+1] = v.y; hv[q*4+2] = v.z; hv[q*4+3] = v.w;
    }
#pragma unroll
    for (int c = 0; c < HID; ++c) {
        float hc = hv[c];
#pragma unroll
        for (int j = 0; j < HID; ++j) d1[j] = fmaf(hc, Wd1[c * HID + j], d1[j]);
    }
    h4 = (const float4*)(h + (size_t)d * HID);
#pragma unroll
    for (int q = 0; q < 4; ++q) {
        float4 v = h4[q];
        hv[q*4+0] = v.x; hv[q*4+1] = v.y; hv[q*4+2] = v.z; hv[q*4+3] = v.w;
    }
#pragma unroll
    for (int c = 0; c < HID; ++c) {
        float hc = hv[c];
#pragma unroll
        for (int j = 0; j < HID; ++j) d1[j] = fmaf(hc, Wd1[(HID + c) * HID + j], d1[j]);
    }
#pragma unroll
    for (int j = 0; j < HID; ++j) d1[j] = fmaxf(d1[j], 0.0f);

    float d2[HID];
#pragma unroll
    for (int j = 0; j < HID; ++j) d2[j] = bd2[j];
#pragma unroll
    for (int c = 0; c < HID; ++c) {
        float dc = d1[c];
#pragma unroll
        for (int j = 0; j < HID; ++j) d2[j] = fmaf(dc, Wd2[c * HID + j], d2[j]);
    }

    float o = bd3[0];
#pragma unroll
    for (int j = 0; j < HID; ++j) o = fmaf(fmaxf(d2[j], 0.0f), Wd3[j], o);

    out[e] = 1.0f / (1.0f + __expf(-o));
}

// ---------------------------------------------------------------------------
extern "C" void kernel_launch(void* const* d_in, const int* in_sizes, int n_in,
                              void* d_out, int out_size, void* d_ws, size_t ws_size,
                              hipStream_t stream) {
    const float* x      = (const float*)d_in[0];
    const int*   edge   = (const int*)d_in[1];   // (2,E): src row then dst row
    const int*   region = (const int*)d_in[2];
    const float* W_in1  = (const float*)d_in[3];
    const float* b_in1  = (const float*)d_in[4];
    const float* W_out1 = (const float*)d_in[5];
    const float* b_out1 = (const float*)d_in[6];
    const float* W_in2  = (const float*)d_in[7];
    const float* b_in2  = (const float*)d_in[8];
    const float* W_out2 = (const float*)d_in[9];
    const float* b_out2 = (const float*)d_in[10];
    const float* W_in3  = (const float*)d_in[11];
    const float* b_in3  = (const float*)d_in[12];
    const float* W_out3 = (const float*)d_in[13];
    const float* b_out3 = (const float*)d_in[14];
    const float* Wd1    = (const float*)d_in[15];
    const float* bd1    = (const float*)d_in[16];
    const float* Wd2    = (const float*)d_in[17];
    const float* bd2    = (const float*)d_in[18];
    const float* Wd3    = (const float*)d_in[19];
    const float* bd3    = (const float*)d_in[20];
    float* out = (float*)d_out;

    const int* src = edge;
    const int* dst = edge + N_EDGES;

    // workspace (~20 MB of 268 MB):
    //   hA[800000 f] hB[800000 f]
    //   cnt_all/cnt_act/row_ptr/cursor[50000 i] blockSums[256 i] invDeg[50000 f]
    //   recs[800000 float4]  (16B aligned)
    float* ws        = (float*)d_ws;
    float* hA        = ws;
    float* hB        = hA + N_NODES * HID;
    int*   cnt_all   = (int*)(hB + N_NODES * HID);
    int*   cnt_act   = cnt_all + N_NODES;
    int*   row_ptr   = cnt_act + N_NODES;
    int*   cursor    = row_ptr + N_NODES;
    int*   blockSums = cursor + N_NODES;
    float* invDeg    = (float*)(blockSums + 256);
    // align recs to 16B: current offset = (1600000+4*50000+256+50000)*4 B = 7,401,024 B (16B-divisible)
    float4* recs     = (float4*)(invDeg + N_NODES);

    const int egrid = N_EDGES / BLK;          // 3125, exact
    const int lgrid = N_NODES * HID / BLK;    // 3125, exact

    // zero cnt_all + cnt_act only (cursor is initialized by scanBC)
    hipMemsetAsync(cnt_all, 0, (size_t)(2 * N_NODES) * sizeof(int), stream);

    count_kernel<<<egrid, BLK, 0, stream>>>(src, dst, region, cnt_all, cnt_act);
    scanA_kernel<<<SCAN_BLOCKS, 256, 0, stream>>>(cnt_act, blockSums);
    scanBC_kernel<<<SCAN_BLOCKS, 256, 0, stream>>>(cnt_act, cnt_all, blockSums,
                                                   row_ptr, cursor, invDeg);
    fill_kernel<<<egrid, BLK, 0, stream>>>(src, dst, region, x, cursor, recs);

    gather_kernel<14><<<lgrid, BLK, 0, stream>>>(x + 2, recs, row_ptr, cnt_act, invDeg,
                                                 W_in1, b_in1, W_out1, b_out1, hA);
    gather_kernel<16><<<lgrid, BLK, 0, stream>>>(hA, recs, row_ptr, cnt_act, invDeg,
                                                 W_in2, b_in2, W_out2, b_out2, hB);
    gather_kernel<16><<<lgrid, BLK, 0, stream>>>(hB, recs, row_ptr, cnt_act, invDeg,
                                                 W_in3, b_in3, W_out3, b_out3, hA);

    decoder_kernel<<<egrid, BLK, 0, stream>>>(hA, src, dst, Wd1, bd1, Wd2, bd2, Wd3, bd3, out);
}